// Round 22
// baseline (125.509 us; speedup 1.0000x reference)
//
#include <hip/hip_runtime.h>
#include <math.h>

#define B_   8
#define S_   1024
#define NXc  768
#define H_   12
#define HDc  64
#define M_   (B_*S_)        // 8192
#define NQKV (3*NXc)        // 2304

typedef __attribute__((ext_vector_type(8))) short short8;
typedef __attribute__((ext_vector_type(8))) _Float16 half8;
typedef __attribute__((ext_vector_type(4))) float f32x4;

__device__ inline unsigned short f2h(float f) {
  union { _Float16 h; unsigned short u; } c;
  c.h = (_Float16)f;                 // RNE
  return c.u;
}

__device__ inline void gl_lds16(const unsigned short* g, unsigned short* l) {
  __builtin_amdgcn_global_load_lds(
      (const __attribute__((address_space(1))) void*)g,
      (__attribute__((address_space(3))) void*)l, 16, 0, 0);
}

// ---- workspace layout (floats) ----
static const size_t UA_OFF_F  = 0;                                   // fp16 Ut attn [NQKV][NXc]
static const size_t UA_F_CNT  = ((size_t)NQKV * NXc + 1) / 2;
static const size_t UP_OFF_F  = UA_OFF_F + UA_F_CNT;                 // fp16 Ut proj [NXc][NXc]
static const size_t UP_F_CNT  = ((size_t)NXc * NXc + 1) / 2;
static const size_t QH_OFF_F  = UP_OFF_F + UP_F_CNT;                 // fp16 int q [B,H,S,64]
static const size_t HALF_CNT  = ((size_t)M_ * NXc + 1) / 2;
static const size_t KH_OFF_F  = QH_OFF_F + HALF_CNT;                 // fp16 int k [B,H,S,64]
static const size_t VHT_OFF_F = KH_OFF_F + HALF_CNT;                 // fp16 int v^T [B,H,64,S]
static const size_t AHF_OFF_F = VHT_OFF_F + HALF_CNT;                // fp16 attn out (xh earlier)
static const size_t SC_OFF    = AHF_OFF_F + HALF_CNT;                // 256 partial-max floats
static const size_t WS_FLOATS_NEEDED = SC_OFF + 256;

// ---------------- fused prep: x->fp16 (blocks 0..3071) + max|w| partials -----
__global__ __launch_bounds__(256) void k_prep(
    const float* __restrict__ x, unsigned short* __restrict__ xh,
    const float* __restrict__ wa, const float* __restrict__ wp,
    float* __restrict__ scp) {
  const int bid = blockIdx.x;
  if (bid < 3072) {                      // xhalf: 3072*256*8 = M_*NXc exactly
    int i = bid * 256 + threadIdx.x;
    const float* src = x + (size_t)i * 8;
    float4 f0 = *(const float4*)src;
    float4 f1 = *(const float4*)(src + 4);
    float fv[8] = {f0.x, f0.y, f0.z, f0.w, f1.x, f1.y, f1.z, f1.w};
    union { short8 v; unsigned short u[8]; } o;
#pragma unroll
    for (int j = 0; j < 8; ++j) o.u[j] = f2h(fv[j]);
    *(short8*)(xh + (size_t)i * 8) = o.v;
  } else {                               // |w| partial max: 128 blocks/tensor
    __shared__ float wpart[4];
    const int which = (bid - 3072) >> 7;
    const int xb = (bid - 3072) & 127;
    const float* w = which ? wp : wa;
    const int n = which ? (NXc * NXc) : (NXc * NQKV);
    float mx = 0.f;
    for (int i = xb * 256 + threadIdx.x; i < n; i += 128 * 256)
      mx = fmaxf(mx, fabsf(w[i]));
#pragma unroll
    for (int off = 32; off > 0; off >>= 1)
      mx = fmaxf(mx, __shfl_xor(mx, off));
    if ((threadIdx.x & 63) == 0) wpart[threadIdx.x >> 6] = mx;
    __syncthreads();
    if (threadIdx.x == 0)
      scp[which * 128 + xb] =
          fmaxf(fmaxf(wpart[0], wpart[1]), fmaxf(wpart[2], wpart[3]));
  }
}

// ---------------- weight quant -> transposed exact-fp16 integer weights ------
__global__ __launch_bounds__(256) void k_quantw2(
    const float* __restrict__ wa, const float* __restrict__ wp,
    unsigned short* __restrict__ ua, unsigned short* __restrict__ up,
    const float* __restrict__ scp) {
  __shared__ unsigned short Ut[64][72];
  __shared__ float wred[4];
  const int bid = blockIdx.x;
  const int isp = (bid >= 432);
  const float* w = isp ? wp : wa;
  unsigned short* ut = isp ? up : ua;
  const int N = isp ? NXc : NQKV;
  const int K = NXc;
  const int idx = isp ? (bid - 432) : bid;
  const int nb = isp ? 12 : 36;
  const int bx = idx % nb, by = idx / nb;
  const int t = threadIdx.x;

  {
    float m = scp[isp * 128 + (t & 127)];
#pragma unroll
    for (int off = 32; off > 0; off >>= 1) m = fmaxf(m, __shfl_xor(m, off));
    if ((t & 63) == 0) wred[t >> 6] = m;
  }
  __syncthreads();
  const float gmax = fmaxf(fmaxf(wred[0], wred[1]), fmaxf(wred[2], wred[3]));
  const float inv2m = 0.5f / tanhf(gmax);

  const int k0 = by * 64, n0 = bx * 64;
  const int r = t >> 4, c4 = (t & 15) * 4;
#pragma unroll
  for (int rr = 0; rr < 4; ++rr) {
    int row = rr * 16 + r;
    float4 f = *(const float4*)(w + (size_t)(k0 + row) * N + n0 + c4);
    float fv[4] = {f.x, f.y, f.z, f.w};
#pragma unroll
    for (int j = 0; j < 4; ++j) {
      float tq = tanhf(fv[j]) * inv2m + 0.5f;
      float u = 2.0f * rintf(tq * 255.0f) - 255.0f;
      Ut[c4 + j][row] = f2h(u);
    }
  }
  __syncthreads();
#pragma unroll
  for (int rep = 0; rep < 2; ++rep) {
    int c = t + rep * 256;
    int n = c >> 3, slot = c & 7;
    short8 v = *(const short8*)&Ut[n][slot * 8];
    *(short8*)(ut + (size_t)(n0 + n) * K + k0 + slot * 8) = v;
  }
}

// ---------------- qkv GEMM (r16 exact): 128x256, 4 waves 64x128, BK=32 -------
__global__ __launch_bounds__(256, 2) void k_gemm_qkv(
    const unsigned short* __restrict__ xh, const unsigned short* __restrict__ ua,
    const float* __restrict__ bias,
    unsigned short* __restrict__ qh, unsigned short* __restrict__ kh,
    unsigned short* __restrict__ vht, float* __restrict__ kq, float* __restrict__ vq) {
  __shared__ __align__(16) unsigned short SMEM[3 * 12288];   // 72 KB
  unsigned short* Ahb3 = SMEM;                 // 3 x 4096 (A: 128x32)
  unsigned short* Bsb3 = SMEM + 3 * 4096;      // 3 x 8192 (B: 256x32)
  unsigned short* T    = SMEM;                 // epilogue alias

  const int bid = blockIdx.x;                  // 576, %8==0
  const int swz = (bid & 7) * 72 + (bid >> 3);
  const int bm = swz / 9, bn = swz % 9;
  const int part = bn / 3;

  const int t = threadIdx.x;
  const int w = t >> 6, lane = t & 63;
  const int wm = w >> 1, wn = w & 1;
  const int g = lane >> 4, ln = lane & 15;

  const unsigned short* Ab = xh + (size_t)bm * 128 * NXc;
  const unsigned short* Bb = ua + (size_t)bn * 256 * NXc;

  const int srow = t >> 2;
  const int aco  = (((t & 3) ^ ((t >> 3) & 3)) << 3);
  const int rsw  = ((g ^ ((ln >> 1) & 3)) << 3);

  f32x4 acc[4][8];
#pragma unroll
  for (int i = 0; i < 4; ++i)
#pragma unroll
    for (int j = 0; j < 8; ++j) acc[i][j] = (f32x4)(0.f);

  auto STAGE = [&](int tk, int buf) {
    const int k0 = tk * 32;
    unsigned short* Ah = Ahb3 + buf * 4096;
    unsigned short* Bs = Bsb3 + buf * 8192;
    gl_lds16(Ab + (size_t)srow * NXc + k0 + aco, &Ah[t * 8]);
    gl_lds16(Ab + (size_t)(srow + 64) * NXc + k0 + aco, &Ah[(256 + t) * 8]);
#pragma unroll
    for (int rr = 0; rr < 4; ++rr)
      gl_lds16(Bb + (size_t)(srow + rr * 64) * NXc + k0 + aco, &Bs[(rr * 256 + t) * 8]);
  };
  auto COMPUTE = [&](int buf) {
    const unsigned short* Ah = Ahb3 + buf * 4096;
    const unsigned short* Bs = Bsb3 + buf * 8192;
    half8 bfrag[8];
#pragma unroll
    for (int nf = 0; nf < 8; ++nf)
      bfrag[nf] = *(const half8*)&Bs[(wn * 128 + nf * 16 + ln) * 32 + rsw];
#pragma unroll
    for (int mf = 0; mf < 4; ++mf) {
      half8 ah = *(const half8*)&Ah[(wm * 64 + mf * 16 + ln) * 32 + rsw];
#pragma unroll
      for (int nf = 0; nf < 8; ++nf)
        acc[mf][nf] = __builtin_amdgcn_mfma_f32_16x16x32_f16(ah, bfrag[nf], acc[mf][nf], 0, 0, 0);
    }
  };

  STAGE(0, 0);
  STAGE(1, 1);
  for (int tk = 0; tk < 22; ++tk) {
    asm volatile("s_waitcnt vmcnt(6)" ::: "memory");
    __builtin_amdgcn_s_barrier();
    STAGE(tk + 2, (tk + 2) % 3);
    COMPUTE(tk % 3);
  }
  asm volatile("s_waitcnt vmcnt(6)" ::: "memory");
  __builtin_amdgcn_s_barrier();
  COMPUTE(22 % 3);
  asm volatile("s_waitcnt vmcnt(0)" ::: "memory");
  __builtin_amdgcn_s_barrier();
  COMPUTE(23 % 3);

  const float inv255 = 1.0f / 255.0f;
  if (part == 2) {
    __syncthreads();
#pragma unroll
    for (int mf = 0; mf < 4; ++mf) {
      int row0 = bm * 128 + wm * 64 + mf * 16 + g * 4;
#pragma unroll
      for (int nf = 0; nf < 8; ++nf) {
        int c = wn * 128 + nf * 16 + ln;
        int col = bn * 256 + c;
        float bv255 = bias[col] * 255.0f;
        int ff = col - 2 * NXc;
        int h = ff >> 6, d = ff & 63;
#pragma unroll
        for (int r = 0; r < 4; ++r) {
          float y255 = rintf(fminf(fmaxf(acc[mf][nf][r] + bv255, 0.f), 255.f));
          int row = row0 + r;
          int b = row >> 10, s = row & 1023;
          vq[(((size_t)b * H_ + h) * S_ + s) * HDc + d] = y255 * inv255;
          int sl = wm * 64 + mf * 16 + g * 4 + r;
          T[c * 136 + sl] = f2h(y255);
        }
      }
    }
    __syncthreads();
    const int bB = bm >> 3;
    const int s0 = (bm & 7) * 128;
    const int h0 = (bn - 6) * 4;
#pragma unroll
    for (int rep = 0; rep < 16; ++rep) {
      int idx = rep * 256 + t;
      int c = idx >> 4, sc2 = idx & 15;
      short8 v = *(const short8*)&T[c * 136 + sc2 * 8];
      int h = h0 + (c >> 6), d = c & 63;
      *(short8*)(vht + (((size_t)bB * H_ + h) * HDc + d) * S_ + s0 + sc2 * 8) = v;
    }
  } else {
    __syncthreads();
#pragma unroll
    for (int mf = 0; mf < 4; ++mf) {
      int lrow0 = wm * 64 + mf * 16 + g * 4;
#pragma unroll
      for (int nf = 0; nf < 8; ++nf) {
        int lcol = wn * 128 + nf * 16 + ln;
        float bv255 = bias[bn * 256 + lcol] * 255.0f;
#pragma unroll
        for (int r = 0; r < 4; ++r) {
          float y255 = rintf(fminf(fmaxf(acc[mf][nf][r] + bv255, 0.f), 255.f));
          T[(lrow0 + r) * 264 + lcol] = f2h(y255);
        }
      }
    }
    __syncthreads();
#pragma unroll
    for (int rep = 0; rep < 16; ++rep) {
      int idx = rep * 256 + t;
      int row = idx >> 5, cc = idx & 31;
      short8 v = *(const short8*)&T[row * 264 + cc * 8];
      int grow = bm * 128 + row;
      int b = grow >> 10, s = grow & 1023;
      int col = bn * 256 + cc * 8;
      int ff = col - part * NXc;
      int h = ff >> 6, d0 = ff & 63;
      size_t dst = (((size_t)b * H_ + h) * S_ + s) * HDc + d0;
      if (part == 0) {
        *(short8*)(qh + dst) = v;
      } else {
        *(short8*)(kh + dst) = v;
        union { short8 s8; half8 h8; } cvt; cvt.s8 = v;
        float4 f0, f1;
        f0.x = (float)cvt.h8[0] * inv255; f0.y = (float)cvt.h8[1] * inv255;
        f0.z = (float)cvt.h8[2] * inv255; f0.w = (float)cvt.h8[3] * inv255;
        f1.x = (float)cvt.h8[4] * inv255; f1.y = (float)cvt.h8[5] * inv255;
        f1.z = (float)cvt.h8[6] * inv255; f1.w = (float)cvt.h8[7] * inv255;
        *(float4*)(kq + dst) = f0;
        *(float4*)(kq + dst + 4) = f1;
      }
    }
  }
}

// ---------------- proj GEMM (r16 exact): 64x128 tile, BK=32, 3-stage ---------
__global__ __launch_bounds__(256, 4) void k_gemm_proj(
    const unsigned short* __restrict__ ahf, const unsigned short* __restrict__ up,
    const float* __restrict__ bias, float* __restrict__ Cout) {
  __shared__ __align__(16) unsigned short SMEM[3 * (2048 + 4096)];   // 36 KB
  unsigned short* Ahb3 = SMEM;
  unsigned short* Bsb3 = SMEM + 3 * 2048;

  const int bid = blockIdx.x;
  const int swz = (bid & 7) * 96 + (bid >> 3);
  const int bm = swz / 6, bn = swz % 6;

  const int t = threadIdx.x;
  const int w = t >> 6, lane = t & 63;
  const int wm = w >> 1, wn = w & 1;
  const int g = lane >> 4, ln = lane & 15;

  const unsigned short* Ab = ahf + (size_t)bm * 64 * NXc;
  const unsigned short* Bb = up + (size_t)bn * 128 * NXc;

  const int srow = t >> 2;
  const int aco  = (((t & 3) ^ ((t >> 3) & 3)) << 3);
  const int rsw  = ((g ^ ((ln >> 1) & 3)) << 3);

  f32x4 acc[2][4];
#pragma unroll
  for (int i = 0; i < 2; ++i)
#pragma unroll
    for (int j = 0; j < 4; ++j) acc[i][j] = (f32x4)(0.f);

  auto STAGE = [&](int tk, int buf) {
    const int k0 = tk * 32;
    unsigned short* Ah = Ahb3 + buf * 2048;
    unsigned short* Bs = Bsb3 + buf * 4096;
    gl_lds16(Ab + (size_t)srow * NXc + k0 + aco, &Ah[t * 8]);
    gl_lds16(Bb + (size_t)srow * NXc + k0 + aco, &Bs[t * 8]);
    gl_lds16(Bb + (size_t)(srow + 64) * NXc + k0 + aco, &Bs[(256 + t) * 8]);
  };
  auto COMPUTE = [&](int buf) {
    const unsigned short* Ah = Ahb3 + buf * 2048;
    const unsigned short* Bs = Bsb3 + buf * 4096;
    half8 bfrag[4];
#pragma unroll
    for (int nf = 0; nf < 4; ++nf)
      bfrag[nf] = *(const half8*)&Bs[(wn * 64 + nf * 16 + ln) * 32 + rsw];
#pragma unroll
    for (int mf = 0; mf < 2; ++mf) {
      half8 ah = *(const half8*)&Ah[(wm * 32 + mf * 16 + ln) * 32 + rsw];
#pragma unroll
      for (int nf = 0; nf < 4; ++nf)
        acc[mf][nf] = __builtin_amdgcn_mfma_f32_16x16x32_f16(ah, bfrag[nf], acc[mf][nf], 0, 0, 0);
    }
  };

  STAGE(0, 0);
  STAGE(1, 1);
  for (int tk = 0; tk < 22; ++tk) {
    asm volatile("s_waitcnt vmcnt(3)" ::: "memory");
    __builtin_amdgcn_s_barrier();
    __builtin_amdgcn_sched_barrier(0);
    STAGE(tk + 2, (tk + 2) % 3);
    COMPUTE(tk % 3);
  }
  asm volatile("s_waitcnt vmcnt(3)" ::: "memory");
  __builtin_amdgcn_s_barrier();
  __builtin_amdgcn_sched_barrier(0);
  COMPUTE(22 % 3);
  asm volatile("s_waitcnt vmcnt(0)" ::: "memory");
  __builtin_amdgcn_s_barrier();
  __builtin_amdgcn_sched_barrier(0);
  COMPUTE(23 % 3);

  const float inv255 = 1.0f / 255.0f;
#pragma unroll
  for (int mf = 0; mf < 2; ++mf) {
    int row0 = bm * 64 + wm * 32 + mf * 16 + g * 4;
#pragma unroll
    for (int nf = 0; nf < 4; ++nf) {
      int col = bn * 128 + wn * 64 + nf * 16 + ln;
      float bv = bias[col];
#pragma unroll
      for (int r = 0; r < 4; ++r)
        Cout[(size_t)(row0 + r) * NXc + col] = acc[mf][nf][r] * inv255 + bv;
    }
  }
}

// ---------------- MFMA causal flash attention: 1 q-block/WG, longest-first ----
// grid 1536 = 8 xcd x 192; gidx=(bid&7)*192+(bid>>3); hid=gidx>>4;
// iq = 15 - (gidx&15) -> within each XCD chunk, long q-blocks dispatch first
// (tail packing). 4 blocks/CU resident (40 KB LDS), 6/CU available -> more
// cross-block phase diversity to hide per-tile barrier stalls.
__global__ __launch_bounds__(256, 4) void k_attn_one(
    const unsigned short* __restrict__ qh, const unsigned short* __restrict__ kh,
    const unsigned short* __restrict__ vht, unsigned short* __restrict__ ahf) {
  __shared__ __align__(16) unsigned short Ks[2][64 * 64];   // [kv][d]^((kv&7)<<3)
  __shared__ __align__(16) unsigned short Vt[2][64 * 64];   // [d][kv]^((d&7)<<3)
  __shared__ __align__(16) unsigned short Pp[4 * 16 * 64];  // per-wave P

  const int bid = blockIdx.x;                  // 1536 = 8 xcd x 192
  const int gidx = (bid & 7) * 192 + (bid >> 3);
  const int hid = gidx >> 4;                   // head 0..95 (12 per XCD)
  const int iq = 15 - (gidx & 15);             // longest (iq=15) first
  const int b = hid / H_, h = hid - b * H_;

  const size_t hoff = (size_t)hid * S_ * HDc;
  const unsigned short* qhp = qh + hoff;
  const unsigned short* khp = kh + hoff;
  const unsigned short* vhp = vht + hoff;

  const int t = threadIdx.x;
  const int w = t >> 6, lane = t & 63;
  const int g = lane >> 4, ln = lane & 15;

  const int r0 = t >> 3, c0 = (((t & 7) ^ (r0 & 7)) << 3);
  const int r1 = 32 + (t >> 3), c1 = (((t & 7) ^ (r1 & 7)) << 3);

  auto STAGE = [&](int jb, int buf) {
    gl_lds16(khp + (size_t)(jb * 64 + r0) * HDc + c0, &Ks[buf][t * 8]);
    gl_lds16(khp + (size_t)(jb * 64 + r1) * HDc + c1, &Ks[buf][(256 + t) * 8]);
    gl_lds16(vhp + (size_t)r0 * S_ + jb * 64 + c0, &Vt[buf][t * 8]);
    gl_lds16(vhp + (size_t)r1 * S_ + jb * 64 + c1, &Vt[buf][(256 + t) * 8]);
  };

  const float SCALE = 1.0f / (255.0f * 255.0f * 8.0f);

  half8 qfrag[2];
  {
    const unsigned short* qr = qhp + (size_t)(iq * 64 + w * 16 + ln) * HDc;
    qfrag[0] = *(const half8*)(qr + g * 8);
    qfrag[1] = *(const half8*)(qr + 32 + g * 8);
  }

  float l[4];
  f32x4 accO[4];
#pragma unroll
  for (int r = 0; r < 4; ++r) l[r] = 0.f;
#pragma unroll
  for (int nf = 0; nf < 4; ++nf) accO[nf] = (f32x4)(0.f);

  STAGE(0, 0);
  for (int i = 0; i <= iq; ++i) {
    const int buf = i & 1;
    __syncthreads();
    if (i < iq) STAGE(i + 1, buf ^ 1);

    f32x4 accS[4];
#pragma unroll
    for (int nf = 0; nf < 4; ++nf) accS[nf] = (f32x4)(0.f);
    __builtin_amdgcn_s_setprio(1);
#pragma unroll
    for (int ks = 0; ks < 2; ++ks)
#pragma unroll
      for (int nf = 0; nf < 4; ++nf) {
        int kvr = nf * 16 + ln;
        half8 bk = *(const half8*)&Ks[buf][kvr * 64 + ((ks * 32 + g * 8) ^ ((kvr & 7) << 3))];
        accS[nf] = __builtin_amdgcn_mfma_f32_16x16x32_f16(qfrag[ks], bk, accS[nf], 0, 0, 0);
      }
    __builtin_amdgcn_s_setprio(0);

    float pr[4][4];
    if (i == iq) {                       // diagonal tile
      const int grow = iq * 64 + w * 16 + g * 4;
      const int gcol = i * 64 + ln;
#pragma unroll
      for (int nf = 0; nf < 4; ++nf)
#pragma unroll
        for (int r = 0; r < 4; ++r) {
          float pv = (gcol + nf * 16 > grow + r) ? 0.f : __expf(accS[nf][r] * SCALE);
          pr[nf][r] = pv;
          l[r] += pv;
        }
    } else {
#pragma unroll
      for (int nf = 0; nf < 4; ++nf)
#pragma unroll
        for (int r = 0; r < 4; ++r) {
          float pv = __expf(accS[nf][r] * SCALE);
          pr[nf][r] = pv;
          l[r] += pv;
        }
    }

#pragma unroll
    for (int nf = 0; nf < 4; ++nf)
#pragma unroll
      for (int r = 0; r < 4; ++r) {
        int prow = g * 4 + r;
        Pp[w * 1024 + prow * 64 + ((nf * 16 + ln) ^ ((prow & 7) << 3))] = f2h(pr[nf][r]);
      }

    __builtin_amdgcn_s_setprio(1);
#pragma unroll
    for (int ks = 0; ks < 2; ++ks) {
      half8 pa = *(const half8*)&Pp[w * 1024 + ln * 64 + ((ks * 32 + g * 8) ^ ((ln & 7) << 3))];
#pragma unroll
      for (int nf = 0; nf < 4; ++nf) {
        int d = nf * 16 + ln;
        half8 bv = *(const half8*)&Vt[buf][d * 64 + ((ks * 32 + g * 8) ^ ((d & 7) << 3))];
        accO[nf] = __builtin_amdgcn_mfma_f32_16x16x32_f16(pa, bv, accO[nf], 0, 0, 0);
      }
    }
    __builtin_amdgcn_s_setprio(0);
  }

  // writeout (row-reduce l once)
#pragma unroll
  for (int off = 1; off < 16; off <<= 1)
#pragma unroll
    for (int r = 0; r < 4; ++r) l[r] += __shfl_xor(l[r], off);
#pragma unroll
  for (int r = 0; r < 4; ++r) {
    float inv = 1.0f / (255.0f * l[r]);
    size_t row = (size_t)b * S_ + iq * 64 + w * 16 + g * 4 + r;
#pragma unroll
    for (int nf = 0; nf < 4; ++nf)
      ahf[row * NXc + h * HDc + nf * 16 + ln] = f2h(accO[nf][r] * inv);
  }
}

// ---------------- host launcher ----------------
extern "C" void kernel_launch(void* const* d_in, const int* in_sizes, int n_in,
                              void* d_out, int out_size, void* d_ws, size_t ws_size,
                              hipStream_t stream) {
  const float* x      = (const float*)d_in[0];
  const float* W_attn = (const float*)d_in[1];
  const float* b_attn = (const float*)d_in[2];
  const float* W_proj = (const float*)d_in[3];
  const float* b_proj = (const float*)d_in[4];

  float* out = (float*)d_out;
  float* ws  = (float*)d_ws;
  if (ws_size < WS_FLOATS_NEEDED * sizeof(float)) return;

  float* a_out = out;                               // [B,S,NX]
  float* k_out = out + (size_t)M_ * NXc;            // present[0] = k
  float* v_out = k_out + (size_t)M_ * NXc;          // present[1] = v

  unsigned short* ua  = (unsigned short*)(ws + UA_OFF_F);
  unsigned short* up  = (unsigned short*)(ws + UP_OFF_F);
  unsigned short* qh  = (unsigned short*)(ws + QH_OFF_F);
  unsigned short* kh  = (unsigned short*)(ws + KH_OFF_F);
  unsigned short* vht = (unsigned short*)(ws + VHT_OFF_F);
  unsigned short* ahf = (unsigned short*)(ws + AHF_OFF_F);
  float* scp = ws + SC_OFF;                         // 256 partial-max slots

  unsigned short* xh = ahf;   // region reuse: attn writes ahf only after qkv read xh

  // fused: x->fp16 + |w| partial maxima (no memset, no atomics)
  k_prep<<<3328, 256, 0, stream>>>(x, xh, W_attn, W_proj, scp);

  // fused: reduce partials + quantize+transpose both weight tensors
  k_quantw2<<<576, 256, 0, stream>>>(W_attn, W_proj, ua, up, scp);

  // qkv = x @ wq_attn + b_attn (fp16 MFMA, counted pipeline)
  k_gemm_qkv<<<(NQKV / 256) * (M_ / 128), 256, 0, stream>>>(
      xh, ua, b_attn, qh, kh, vht, k_out, v_out);

  // causal attention (1 q-block/WG, longest-first, head-chunked XCD swizzle)
  k_attn_one<<<1536, 256, 0, stream>>>(qh, kh, vht, ahf);

  // a = attn_out @ wq_proj + b_proj
  k_gemm_proj<<<(NXc / 128) * (M_ / 64), 256, 0, stream>>>(ahf, up, b_proj, a_out);
}

// Round 23
// 118.126 us; speedup vs baseline: 1.0625x; 1.0625x over previous
//
#include <hip/hip_runtime.h>
#include <math.h>

#define B_   8
#define S_   1024
#define NXc  768
#define H_   12
#define HDc  64
#define M_   (B_*S_)        // 8192
#define NQKV (3*NXc)        // 2304

typedef __attribute__((ext_vector_type(8))) short short8;
typedef __attribute__((ext_vector_type(8))) _Float16 half8;
typedef __attribute__((ext_vector_type(4))) float f32x4;

__device__ inline unsigned short f2h(float f) {
  union { _Float16 h; unsigned short u; } c;
  c.h = (_Float16)f;                 // RNE
  return c.u;
}

__device__ inline void gl_lds16(const unsigned short* g, unsigned short* l) {
  __builtin_amdgcn_global_load_lds(
      (const __attribute__((address_space(1))) void*)g,
      (__attribute__((address_space(3))) void*)l, 16, 0, 0);
}

// ---- workspace layout (floats) ----
static const size_t UA_OFF_F  = 0;                                   // fp16 Ut attn [NQKV][NXc]
static const size_t UA_F_CNT  = ((size_t)NQKV * NXc + 1) / 2;
static const size_t UP_OFF_F  = UA_OFF_F + UA_F_CNT;                 // fp16 Ut proj [NXc][NXc]
static const size_t UP_F_CNT  = ((size_t)NXc * NXc + 1) / 2;
static const size_t QH_OFF_F  = UP_OFF_F + UP_F_CNT;                 // fp16 int q [B,H,S,64]
static const size_t HALF_CNT  = ((size_t)M_ * NXc + 1) / 2;
static const size_t KH_OFF_F  = QH_OFF_F + HALF_CNT;                 // fp16 int k [B,H,S,64]
static const size_t VHT_OFF_F = KH_OFF_F + HALF_CNT;                 // fp16 int v^T [B,H,64,S]
static const size_t AHF_OFF_F = VHT_OFF_F + HALF_CNT;                // fp16 attn out (xh earlier)
static const size_t SC_OFF    = AHF_OFF_F + HALF_CNT;                // 256 partial-max floats
static const size_t WS_FLOATS_NEEDED = SC_OFF + 256;

// ---------------- fused prep: x->fp16 (blocks 0..3071) + max|w| partials -----
__global__ __launch_bounds__(256) void k_prep(
    const float* __restrict__ x, unsigned short* __restrict__ xh,
    const float* __restrict__ wa, const float* __restrict__ wp,
    float* __restrict__ scp) {
  const int bid = blockIdx.x;
  if (bid < 3072) {                      // xhalf: 3072*256*8 = M_*NXc exactly
    int i = bid * 256 + threadIdx.x;
    const float* src = x + (size_t)i * 8;
    float4 f0 = *(const float4*)src;
    float4 f1 = *(const float4*)(src + 4);
    float fv[8] = {f0.x, f0.y, f0.z, f0.w, f1.x, f1.y, f1.z, f1.w};
    union { short8 v; unsigned short u[8]; } o;
#pragma unroll
    for (int j = 0; j < 8; ++j) o.u[j] = f2h(fv[j]);
    *(short8*)(xh + (size_t)i * 8) = o.v;
  } else {                               // |w| partial max: 128 blocks/tensor
    __shared__ float wpart[4];
    const int which = (bid - 3072) >> 7;
    const int xb = (bid - 3072) & 127;
    const float* w = which ? wp : wa;
    const int n = which ? (NXc * NXc) : (NXc * NQKV);
    float mx = 0.f;
    for (int i = xb * 256 + threadIdx.x; i < n; i += 128 * 256)
      mx = fmaxf(mx, fabsf(w[i]));
#pragma unroll
    for (int off = 32; off > 0; off >>= 1)
      mx = fmaxf(mx, __shfl_xor(mx, off));
    if ((threadIdx.x & 63) == 0) wpart[threadIdx.x >> 6] = mx;
    __syncthreads();
    if (threadIdx.x == 0)
      scp[which * 128 + xb] =
          fmaxf(fmaxf(wpart[0], wpart[1]), fmaxf(wpart[2], wpart[3]));
  }
}

// ---------------- weight quant -> transposed exact-fp16 integer weights ------
__global__ __launch_bounds__(256) void k_quantw2(
    const float* __restrict__ wa, const float* __restrict__ wp,
    unsigned short* __restrict__ ua, unsigned short* __restrict__ up,
    const float* __restrict__ scp) {
  __shared__ unsigned short Ut[64][72];
  __shared__ float wred[4];
  const int bid = blockIdx.x;
  const int isp = (bid >= 432);
  const float* w = isp ? wp : wa;
  unsigned short* ut = isp ? up : ua;
  const int N = isp ? NXc : NQKV;
  const int K = NXc;
  const int idx = isp ? (bid - 432) : bid;
  const int nb = isp ? 12 : 36;
  const int bx = idx % nb, by = idx / nb;
  const int t = threadIdx.x;

  {
    float m = scp[isp * 128 + (t & 127)];
#pragma unroll
    for (int off = 32; off > 0; off >>= 1) m = fmaxf(m, __shfl_xor(m, off));
    if ((t & 63) == 0) wred[t >> 6] = m;
  }
  __syncthreads();
  const float gmax = fmaxf(fmaxf(wred[0], wred[1]), fmaxf(wred[2], wred[3]));
  const float inv2m = 0.5f / tanhf(gmax);

  const int k0 = by * 64, n0 = bx * 64;
  const int r = t >> 4, c4 = (t & 15) * 4;
#pragma unroll
  for (int rr = 0; rr < 4; ++rr) {
    int row = rr * 16 + r;
    float4 f = *(const float4*)(w + (size_t)(k0 + row) * N + n0 + c4);
    float fv[4] = {f.x, f.y, f.z, f.w};
#pragma unroll
    for (int j = 0; j < 4; ++j) {
      float tq = tanhf(fv[j]) * inv2m + 0.5f;
      float u = 2.0f * rintf(tq * 255.0f) - 255.0f;
      Ut[c4 + j][row] = f2h(u);
    }
  }
  __syncthreads();
#pragma unroll
  for (int rep = 0; rep < 2; ++rep) {
    int c = t + rep * 256;
    int n = c >> 3, slot = c & 7;
    short8 v = *(const short8*)&Ut[n][slot * 8];
    *(short8*)(ut + (size_t)(n0 + n) * K + k0 + slot * 8) = v;
  }
}

// ---------------- qkv GEMM (r16 exact): 128x256, 4 waves 64x128, BK=32 -------
__global__ __launch_bounds__(256, 2) void k_gemm_qkv(
    const unsigned short* __restrict__ xh, const unsigned short* __restrict__ ua,
    const float* __restrict__ bias,
    unsigned short* __restrict__ qh, unsigned short* __restrict__ kh,
    unsigned short* __restrict__ vht, float* __restrict__ kq, float* __restrict__ vq) {
  __shared__ __align__(16) unsigned short SMEM[3 * 12288];   // 72 KB
  unsigned short* Ahb3 = SMEM;                 // 3 x 4096 (A: 128x32)
  unsigned short* Bsb3 = SMEM + 3 * 4096;      // 3 x 8192 (B: 256x32)
  unsigned short* T    = SMEM;                 // epilogue alias

  const int bid = blockIdx.x;                  // 576, %8==0
  const int swz = (bid & 7) * 72 + (bid >> 3);
  const int bm = swz / 9, bn = swz % 9;
  const int part = bn / 3;

  const int t = threadIdx.x;
  const int w = t >> 6, lane = t & 63;
  const int wm = w >> 1, wn = w & 1;
  const int g = lane >> 4, ln = lane & 15;

  const unsigned short* Ab = xh + (size_t)bm * 128 * NXc;
  const unsigned short* Bb = ua + (size_t)bn * 256 * NXc;

  const int srow = t >> 2;
  const int aco  = (((t & 3) ^ ((t >> 3) & 3)) << 3);
  const int rsw  = ((g ^ ((ln >> 1) & 3)) << 3);

  f32x4 acc[4][8];
#pragma unroll
  for (int i = 0; i < 4; ++i)
#pragma unroll
    for (int j = 0; j < 8; ++j) acc[i][j] = (f32x4)(0.f);

  auto STAGE = [&](int tk, int buf) {
    const int k0 = tk * 32;
    unsigned short* Ah = Ahb3 + buf * 4096;
    unsigned short* Bs = Bsb3 + buf * 8192;
    gl_lds16(Ab + (size_t)srow * NXc + k0 + aco, &Ah[t * 8]);
    gl_lds16(Ab + (size_t)(srow + 64) * NXc + k0 + aco, &Ah[(256 + t) * 8]);
#pragma unroll
    for (int rr = 0; rr < 4; ++rr)
      gl_lds16(Bb + (size_t)(srow + rr * 64) * NXc + k0 + aco, &Bs[(rr * 256 + t) * 8]);
  };
  auto COMPUTE = [&](int buf) {
    const unsigned short* Ah = Ahb3 + buf * 4096;
    const unsigned short* Bs = Bsb3 + buf * 8192;
    half8 bfrag[8];
#pragma unroll
    for (int nf = 0; nf < 8; ++nf)
      bfrag[nf] = *(const half8*)&Bs[(wn * 128 + nf * 16 + ln) * 32 + rsw];
#pragma unroll
    for (int mf = 0; mf < 4; ++mf) {
      half8 ah = *(const half8*)&Ah[(wm * 64 + mf * 16 + ln) * 32 + rsw];
#pragma unroll
      for (int nf = 0; nf < 8; ++nf)
        acc[mf][nf] = __builtin_amdgcn_mfma_f32_16x16x32_f16(ah, bfrag[nf], acc[mf][nf], 0, 0, 0);
    }
  };

  STAGE(0, 0);
  STAGE(1, 1);
  for (int tk = 0; tk < 22; ++tk) {
    asm volatile("s_waitcnt vmcnt(6)" ::: "memory");
    __builtin_amdgcn_s_barrier();
    STAGE(tk + 2, (tk + 2) % 3);
    COMPUTE(tk % 3);
  }
  asm volatile("s_waitcnt vmcnt(6)" ::: "memory");
  __builtin_amdgcn_s_barrier();
  COMPUTE(22 % 3);
  asm volatile("s_waitcnt vmcnt(0)" ::: "memory");
  __builtin_amdgcn_s_barrier();
  COMPUTE(23 % 3);

  const float inv255 = 1.0f / 255.0f;
  if (part == 2) {
    __syncthreads();
#pragma unroll
    for (int mf = 0; mf < 4; ++mf) {
      int row0 = bm * 128 + wm * 64 + mf * 16 + g * 4;
#pragma unroll
      for (int nf = 0; nf < 8; ++nf) {
        int c = wn * 128 + nf * 16 + ln;
        int col = bn * 256 + c;
        float bv255 = bias[col] * 255.0f;
        int ff = col - 2 * NXc;
        int h = ff >> 6, d = ff & 63;
#pragma unroll
        for (int r = 0; r < 4; ++r) {
          float y255 = rintf(fminf(fmaxf(acc[mf][nf][r] + bv255, 0.f), 255.f));
          int row = row0 + r;
          int b = row >> 10, s = row & 1023;
          vq[(((size_t)b * H_ + h) * S_ + s) * HDc + d] = y255 * inv255;
          int sl = wm * 64 + mf * 16 + g * 4 + r;
          T[c * 136 + sl] = f2h(y255);
        }
      }
    }
    __syncthreads();
    const int bB = bm >> 3;
    const int s0 = (bm & 7) * 128;
    const int h0 = (bn - 6) * 4;
#pragma unroll
    for (int rep = 0; rep < 16; ++rep) {
      int idx = rep * 256 + t;
      int c = idx >> 4, sc2 = idx & 15;
      short8 v = *(const short8*)&T[c * 136 + sc2 * 8];
      int h = h0 + (c >> 6), d = c & 63;
      *(short8*)(vht + (((size_t)bB * H_ + h) * HDc + d) * S_ + s0 + sc2 * 8) = v;
    }
  } else {
    __syncthreads();
#pragma unroll
    for (int mf = 0; mf < 4; ++mf) {
      int lrow0 = wm * 64 + mf * 16 + g * 4;
#pragma unroll
      for (int nf = 0; nf < 8; ++nf) {
        int lcol = wn * 128 + nf * 16 + ln;
        float bv255 = bias[bn * 256 + lcol] * 255.0f;
#pragma unroll
        for (int r = 0; r < 4; ++r) {
          float y255 = rintf(fminf(fmaxf(acc[mf][nf][r] + bv255, 0.f), 255.f));
          T[(lrow0 + r) * 264 + lcol] = f2h(y255);
        }
      }
    }
    __syncthreads();
#pragma unroll
    for (int rep = 0; rep < 16; ++rep) {
      int idx = rep * 256 + t;
      int row = idx >> 5, cc = idx & 31;
      short8 v = *(const short8*)&T[row * 264 + cc * 8];
      int grow = bm * 128 + row;
      int b = grow >> 10, s = grow & 1023;
      int col = bn * 256 + cc * 8;
      int ff = col - part * NXc;
      int h = ff >> 6, d0 = ff & 63;
      size_t dst = (((size_t)b * H_ + h) * S_ + s) * HDc + d0;
      if (part == 0) {
        *(short8*)(qh + dst) = v;
      } else {
        *(short8*)(kh + dst) = v;
        union { short8 s8; half8 h8; } cvt; cvt.s8 = v;
        float4 f0, f1;
        f0.x = (float)cvt.h8[0] * inv255; f0.y = (float)cvt.h8[1] * inv255;
        f0.z = (float)cvt.h8[2] * inv255; f0.w = (float)cvt.h8[3] * inv255;
        f1.x = (float)cvt.h8[4] * inv255; f1.y = (float)cvt.h8[5] * inv255;
        f1.z = (float)cvt.h8[6] * inv255; f1.w = (float)cvt.h8[7] * inv255;
        *(float4*)(kq + dst) = f0;
        *(float4*)(kq + dst + 4) = f1;
      }
    }
  }
}

// ---------------- proj GEMM (r16 exact): 64x128 tile, BK=32, 3-stage ---------
__global__ __launch_bounds__(256, 4) void k_gemm_proj(
    const unsigned short* __restrict__ ahf, const unsigned short* __restrict__ up,
    const float* __restrict__ bias, float* __restrict__ Cout) {
  __shared__ __align__(16) unsigned short SMEM[3 * (2048 + 4096)];   // 36 KB
  unsigned short* Ahb3 = SMEM;
  unsigned short* Bsb3 = SMEM + 3 * 2048;

  const int bid = blockIdx.x;
  const int swz = (bid & 7) * 96 + (bid >> 3);
  const int bm = swz / 6, bn = swz % 6;

  const int t = threadIdx.x;
  const int w = t >> 6, lane = t & 63;
  const int wm = w >> 1, wn = w & 1;
  const int g = lane >> 4, ln = lane & 15;

  const unsigned short* Ab = ahf + (size_t)bm * 64 * NXc;
  const unsigned short* Bb = up + (size_t)bn * 128 * NXc;

  const int srow = t >> 2;
  const int aco  = (((t & 3) ^ ((t >> 3) & 3)) << 3);
  const int rsw  = ((g ^ ((ln >> 1) & 3)) << 3);

  f32x4 acc[2][4];
#pragma unroll
  for (int i = 0; i < 2; ++i)
#pragma unroll
    for (int j = 0; j < 4; ++j) acc[i][j] = (f32x4)(0.f);

  auto STAGE = [&](int tk, int buf) {
    const int k0 = tk * 32;
    unsigned short* Ah = Ahb3 + buf * 2048;
    unsigned short* Bs = Bsb3 + buf * 4096;
    gl_lds16(Ab + (size_t)srow * NXc + k0 + aco, &Ah[t * 8]);
    gl_lds16(Bb + (size_t)srow * NXc + k0 + aco, &Bs[t * 8]);
    gl_lds16(Bb + (size_t)(srow + 64) * NXc + k0 + aco, &Bs[(256 + t) * 8]);
  };
  auto COMPUTE = [&](int buf) {
    const unsigned short* Ah = Ahb3 + buf * 2048;
    const unsigned short* Bs = Bsb3 + buf * 4096;
    half8 bfrag[4];
#pragma unroll
    for (int nf = 0; nf < 4; ++nf)
      bfrag[nf] = *(const half8*)&Bs[(wn * 64 + nf * 16 + ln) * 32 + rsw];
#pragma unroll
    for (int mf = 0; mf < 2; ++mf) {
      half8 ah = *(const half8*)&Ah[(wm * 32 + mf * 16 + ln) * 32 + rsw];
#pragma unroll
      for (int nf = 0; nf < 4; ++nf)
        acc[mf][nf] = __builtin_amdgcn_mfma_f32_16x16x32_f16(ah, bfrag[nf], acc[mf][nf], 0, 0, 0);
    }
  };

  STAGE(0, 0);
  STAGE(1, 1);
  for (int tk = 0; tk < 22; ++tk) {
    asm volatile("s_waitcnt vmcnt(3)" ::: "memory");
    __builtin_amdgcn_s_barrier();
    __builtin_amdgcn_sched_barrier(0);
    STAGE(tk + 2, (tk + 2) % 3);
    COMPUTE(tk % 3);
  }
  asm volatile("s_waitcnt vmcnt(3)" ::: "memory");
  __builtin_amdgcn_s_barrier();
  __builtin_amdgcn_sched_barrier(0);
  COMPUTE(22 % 3);
  asm volatile("s_waitcnt vmcnt(0)" ::: "memory");
  __builtin_amdgcn_s_barrier();
  __builtin_amdgcn_sched_barrier(0);
  COMPUTE(23 % 3);

  const float inv255 = 1.0f / 255.0f;
#pragma unroll
  for (int mf = 0; mf < 2; ++mf) {
    int row0 = bm * 64 + wm * 32 + mf * 16 + g * 4;
#pragma unroll
    for (int nf = 0; nf < 4; ++nf) {
      int col = bn * 128 + wn * 64 + nf * 16 + ln;
      float bv = bias[col];
#pragma unroll
      for (int r = 0; r < 4; ++r)
        Cout[(size_t)(row0 + r) * NXc + col] = acc[mf][nf][r] * inv255 + bv;
    }
  }
}

// ---------------- MFMA causal flash attention (r21 exact: paired + setprio) ---
__global__ __launch_bounds__(256, 4) void k_attn_pair(
    const unsigned short* __restrict__ qh, const unsigned short* __restrict__ kh,
    const unsigned short* __restrict__ vht, unsigned short* __restrict__ ahf) {
  __shared__ __align__(16) unsigned short Ks[2][64 * 64];   // [kv][d]^((kv&7)<<3)
  __shared__ __align__(16) unsigned short Vt[2][64 * 64];   // [d][kv]^((d&7)<<3)
  __shared__ __align__(16) unsigned short Pp[4 * 16 * 64];  // per-wave P

  const int bid = blockIdx.x;                  // 768 = 8 xcd x 96
  const int gidx = (bid & 7) * 96 + (bid >> 3);
  const int hid = gidx >> 3;                   // head 0..95 (12 per XCD)
  const int p = gidx & 7;
  const int b = hid / H_, h = hid - b * H_;

  const size_t hoff = (size_t)hid * S_ * HDc;
  const unsigned short* qhp = qh + hoff;
  const unsigned short* khp = kh + hoff;
  const unsigned short* vhp = vht + hoff;

  const int t = threadIdx.x;
  const int w = t >> 6, lane = t & 63;
  const int g = lane >> 4, ln = lane & 15;

  const int r0 = t >> 3, c0 = (((t & 7) ^ (r0 & 7)) << 3);
  const int r1 = 32 + (t >> 3), c1 = (((t & 7) ^ (r1 & 7)) << 3);

  auto STAGE = [&](int jb, int buf) {
    gl_lds16(khp + (size_t)(jb * 64 + r0) * HDc + c0, &Ks[buf][t * 8]);
    gl_lds16(khp + (size_t)(jb * 64 + r1) * HDc + c1, &Ks[buf][(256 + t) * 8]);
    gl_lds16(vhp + (size_t)r0 * S_ + jb * 64 + c0, &Vt[buf][t * 8]);
    gl_lds16(vhp + (size_t)r1 * S_ + jb * 64 + c1, &Vt[buf][(256 + t) * 8]);
  };

  const float SCALE = 1.0f / (255.0f * 255.0f * 8.0f);

  int iq = p;
  half8 qfrag[2];
  {
    const unsigned short* qr = qhp + (size_t)(iq * 64 + w * 16 + ln) * HDc;
    qfrag[0] = *(const half8*)(qr + g * 8);
    qfrag[1] = *(const half8*)(qr + 32 + g * 8);
  }

  float l[4];
  f32x4 accO[4];
#pragma unroll
  for (int r = 0; r < 4; ++r) l[r] = 0.f;
#pragma unroll
  for (int nf = 0; nf < 4; ++nf) accO[nf] = (f32x4)(0.f);

  auto WRITEOUT = [&]() {
#pragma unroll
    for (int off = 1; off < 16; off <<= 1)
#pragma unroll
      for (int r = 0; r < 4; ++r) l[r] += __shfl_xor(l[r], off);
#pragma unroll
    for (int r = 0; r < 4; ++r) {
      float inv = 1.0f / (255.0f * l[r]);
      size_t row = (size_t)b * S_ + iq * 64 + w * 16 + g * 4 + r;
#pragma unroll
      for (int nf = 0; nf < 4; ++nf)
        ahf[row * NXc + h * HDc + nf * 16 + ln] = f2h(accO[nf][r] * inv);
    }
  };

  STAGE(0, 0);
  int jb = 0;
  for (int i = 0; i < 17; ++i) {
    const int buf = i & 1;
    __syncthreads();
    if (i + 1 < 17) {
      int njb = (i + 1 <= p) ? (i + 1) : (i - p);
      STAGE(njb, buf ^ 1);
    }

    f32x4 accS[4];
#pragma unroll
    for (int nf = 0; nf < 4; ++nf) accS[nf] = (f32x4)(0.f);
    __builtin_amdgcn_s_setprio(1);
#pragma unroll
    for (int ks = 0; ks < 2; ++ks)
#pragma unroll
      for (int nf = 0; nf < 4; ++nf) {
        int kvr = nf * 16 + ln;
        half8 bk = *(const half8*)&Ks[buf][kvr * 64 + ((ks * 32 + g * 8) ^ ((kvr & 7) << 3))];
        accS[nf] = __builtin_amdgcn_mfma_f32_16x16x32_f16(qfrag[ks], bk, accS[nf], 0, 0, 0);
      }
    __builtin_amdgcn_s_setprio(0);

    float pr[4][4];
    if (jb == iq) {
      const int grow = iq * 64 + w * 16 + g * 4;
      const int gcol = jb * 64 + ln;
#pragma unroll
      for (int nf = 0; nf < 4; ++nf)
#pragma unroll
        for (int r = 0; r < 4; ++r) {
          float pv = (gcol + nf * 16 > grow + r) ? 0.f : __expf(accS[nf][r] * SCALE);
          pr[nf][r] = pv;
          l[r] += pv;
        }
    } else {
#pragma unroll
      for (int nf = 0; nf < 4; ++nf)
#pragma unroll
        for (int r = 0; r < 4; ++r) {
          float pv = __expf(accS[nf][r] * SCALE);
          pr[nf][r] = pv;
          l[r] += pv;
        }
    }

#pragma unroll
    for (int nf = 0; nf < 4; ++nf)
#pragma unroll
      for (int r = 0; r < 4; ++r) {
        int prow = g * 4 + r;
        Pp[w * 1024 + prow * 64 + ((nf * 16 + ln) ^ ((prow & 7) << 3))] = f2h(pr[nf][r]);
      }

    __builtin_amdgcn_s_setprio(1);
#pragma unroll
    for (int ks = 0; ks < 2; ++ks) {
      half8 pa = *(const half8*)&Pp[w * 1024 + ln * 64 + ((ks * 32 + g * 8) ^ ((ln & 7) << 3))];
#pragma unroll
      for (int nf = 0; nf < 4; ++nf) {
        int d = nf * 16 + ln;
        half8 bv = *(const half8*)&Vt[buf][d * 64 + ((ks * 32 + g * 8) ^ ((d & 7) << 3))];
        accO[nf] = __builtin_amdgcn_mfma_f32_16x16x32_f16(pa, bv, accO[nf], 0, 0, 0);
      }
    }
    __builtin_amdgcn_s_setprio(0);

    if (i == p) {
      WRITEOUT();
#pragma unroll
      for (int r = 0; r < 4; ++r) l[r] = 0.f;
#pragma unroll
      for (int nf = 0; nf < 4; ++nf) accO[nf] = (f32x4)(0.f);
      iq = 15 - p;
      const unsigned short* qr2 = qhp + (size_t)(iq * 64 + w * 16 + ln) * HDc;
      qfrag[0] = *(const half8*)(qr2 + g * 8);
      qfrag[1] = *(const half8*)(qr2 + 32 + g * 8);
    } else if (i == 16) {
      WRITEOUT();
    }
    jb = (i + 1 <= p) ? (i + 1) : (i - p);
  }
}

// ---------------- host launcher ----------------
extern "C" void kernel_launch(void* const* d_in, const int* in_sizes, int n_in,
                              void* d_out, int out_size, void* d_ws, size_t ws_size,
                              hipStream_t stream) {
  const float* x      = (const float*)d_in[0];
  const float* W_attn = (const float*)d_in[1];
  const float* b_attn = (const float*)d_in[2];
  const float* W_proj = (const float*)d_in[3];
  const float* b_proj = (const float*)d_in[4];

  float* out = (float*)d_out;
  float* ws  = (float*)d_ws;
  if (ws_size < WS_FLOATS_NEEDED * sizeof(float)) return;

  float* a_out = out;                               // [B,S,NX]
  float* k_out = out + (size_t)M_ * NXc;            // present[0] = k
  float* v_out = k_out + (size_t)M_ * NXc;          // present[1] = v

  unsigned short* ua  = (unsigned short*)(ws + UA_OFF_F);
  unsigned short* up  = (unsigned short*)(ws + UP_OFF_F);
  unsigned short* qh  = (unsigned short*)(ws + QH_OFF_F);
  unsigned short* kh  = (unsigned short*)(ws + KH_OFF_F);
  unsigned short* vht = (unsigned short*)(ws + VHT_OFF_F);
  unsigned short* ahf = (unsigned short*)(ws + AHF_OFF_F);
  float* scp = ws + SC_OFF;                         // 256 partial-max slots

  unsigned short* xh = ahf;   // region reuse: attn writes ahf only after qkv read xh

  // fused: x->fp16 + |w| partial maxima (no memset, no atomics)
  k_prep<<<3328, 256, 0, stream>>>(x, xh, W_attn, W_proj, scp);

  // fused: reduce partials + quantize+transpose both weight tensors
  k_quantw2<<<576, 256, 0, stream>>>(W_attn, W_proj, ua, up, scp);

  // qkv = x @ wq_attn + b_attn (fp16 MFMA, counted pipeline)
  k_gemm_qkv<<<(NQKV / 256) * (M_ / 128), 256, 0, stream>>>(
      xh, ua, b_attn, qh, kh, vht, k_out, v_out);

  // causal attention (paired q-blocks, no-max softmax, XCD head-chunking)
  k_attn_pair<<<768, 256, 0, stream>>>(qh, kh, vht, ahf);

  // a = attn_out @ wq_proj + b_proj
  k_gemm_proj<<<(NXc / 128) * (M_ / 64), 256, 0, stream>>>(ahf, up, b_proj, a_out);
}